// Round 1
// baseline (772.490 us; speedup 1.0000x reference)
//
#include <hip/hip_runtime.h>

// Fold / col2im: B=16, C=64, K=3, H=W=128, PAD=1, STR=DIL=1, LH=LW=128.
// Gather form: out[b,c,h,w] = sum_{a,bk} P[b, c*9+a*3+bk, h+1-a, w+1-bk] (valid only)
//
// v5: thread-coarsened x4 along h.
//  - each thread produces 4 row-stacked float4s (16 output floats) of one bc plane
//  - 36 independent global_load_dwordx4 per thread -> deep memory-level parallelism
//  - 1/4 the threads of v4 -> 1/4 the address-math / shuffle overhead per byte
//  - each 256-thread block owns 32 rows of one bc  -> halo over-read 2/34 (~6%)
//    instead of 2/10 (25%), and 4x fewer concurrent HBM read streams
//  - nontemporal stores: output is never re-read; keep L2/L3 for the halo rows
//
// Column shifts (+/-1) via lane shuffles, as in v4. Lane-31/lane-0 masking
// (first/last) also covers the half-wave row-quad discontinuity at lane 32,
// so the shuffle edge logic is unchanged and remains correct.

typedef float float4v __attribute__((ext_vector_type(4)));

#define FOLD_L   16384                    // plane size LH*LW (floats)
#define FOLD_RPT 4                        // rows per thread
// threads: (16*64 bc) * 32 row-quads * 32 w4 = 1,048,576
#define FOLD_NT  (16 * 64 * 32 * 32)

__global__ __launch_bounds__(256) void fold_gather_v5_kernel(
    const float* __restrict__ x, float* __restrict__ out)
{
    int tid = blockIdx.x * blockDim.x + threadIdx.x;

    int w4 = tid & 31;                    // which float4 within the 128-wide row
    int hq = (tid >> 5) & 31;             // which row-quad
    int bc = tid >> 10;                   // b*64 + c  (0..1023)

    const float* base = x + (size_t)bc * 9 * FOLD_L;
    int w0 = w4 << 2;
    int h0 = hq << 2;

    bool first = (w4 == 0);
    bool last  = (w4 == 31);

    float* ob = out + (size_t)bc * FOLD_L + (size_t)h0 * 128 + w0;

#pragma unroll
    for (int r = 0; r < FOLD_RPT; ++r) {
        int h = h0 + r;
        float4v acc = {0.f, 0.f, 0.f, 0.f};

#pragma unroll
        for (int a = 0; a < 3; ++a) {
            int i = h + 1 - a;
            bool va = ((unsigned)i < 128u);
            int ic = va ? i : 0;                      // clamp; contribution zeroed below
            const float* rb = base + (size_t)(a * 3) * FOLD_L + ic * 128 + w0;

            float4v v0 = *(const float4v*)(rb);               // bk=0 plane (j = w+1)
            float4v v1 = *(const float4v*)(rb + FOLD_L);      // bk=1 plane (j = w)
            float4v v2 = *(const float4v*)(rb + 2 * FOLD_L);  // bk=2 plane (j = w-1)

            float nxt = __shfl_down(v0.x, 1);   // next lane's first elem (col w0+4) of bk=0
            float prv = __shfl_up(v2.w, 1);     // prev lane's last  elem (col w0-1) of bk=2

            float4v s;
            s.x = v0.y + v1.x + (first ? 0.0f : prv);
            s.y = v0.z + v1.y + v2.x;
            s.z = v0.w + v1.z + v2.y;
            s.w = (last ? 0.0f : nxt) + v1.w + v2.z;

            float m = va ? 1.0f : 0.0f;
            acc += m * s;
        }

        __builtin_nontemporal_store(acc, (float4v*)(ob + r * 128));
    }
}

extern "C" void kernel_launch(void* const* d_in, const int* in_sizes, int n_in,
                              void* d_out, int out_size, void* d_ws, size_t ws_size,
                              hipStream_t stream)
{
    const float* x = (const float*)d_in[0];
    float* out = (float*)d_out;

    const int threads = 256;
    const int blocks = FOLD_NT / threads;   // 4096
    fold_gather_v5_kernel<<<blocks, threads, 0, stream>>>(x, out);
}